// Round 1
// baseline (2209.643 us; speedup 1.0000x reference)
//
#include <hip/hip_runtime.h>

typedef unsigned short u16;
typedef unsigned int u32;
typedef __bf16 bf8 __attribute__((ext_vector_type(8)));
typedef float f32x4 __attribute__((ext_vector_type(4)));

#define DD 1024

// ---------- helpers ----------
__device__ __forceinline__ u16 f2bf(float x){
  u32 u = __float_as_uint(x);
  u += 0x7fff + ((u >> 16) & 1);
  return (u16)(u >> 16);
}
__device__ __forceinline__ float wred_sum(float v){
  #pragma unroll
  for(int m=32;m;m>>=1) v += __shfl_xor(v,m);
  return v;
}
__device__ __forceinline__ float wred_max(float v){
  #pragma unroll
  for(int m=32;m;m>>=1) v = fmaxf(v,__shfl_xor(v,m));
  return v;
}
__device__ __forceinline__ double wred_sum_d(double v){
  #pragma unroll
  for(int m=32;m;m>>=1) v += __shfl_xor(v,m);
  return v;
}
__device__ __forceinline__ void gload16(const void* g, void* l){
  __builtin_amdgcn_global_load_lds(
      (const __attribute__((address_space(1))) u32*)g,
      (__attribute__((address_space(3))) u32*)l, 16, 0, 0);
}

// ---------- weight scale: sum |w| (f64 accum) ----------
__global__ void k_wabs(const float* __restrict__ w, size_t n4, double* __restrict__ slot){
  double s = 0.0;
  for(size_t i=(size_t)blockIdx.x*256+threadIdx.x; i<n4; i+=(size_t)gridDim.x*256){
    float4 v = ((const float4*)w)[i];
    s += (double)(fabsf(v.x)+fabsf(v.y)) + (double)(fabsf(v.z)+fabsf(v.w));
  }
  s = wred_sum_d(s);
  __shared__ double red[4];
  if((threadIdx.x&63)==0) red[threadIdx.x>>6]=s;
  __syncthreads();
  if(threadIdx.x==0) atomicAdd(slot, red[0]+red[1]+red[2]+red[3]);
}

struct Counts{ float c[17]; };
__global__ void k_wfin(const double* __restrict__ wsum, float* __restrict__ wscale,
                       float* __restrict__ wrecip, Counts cnt, int nw){
  int j = threadIdx.x;
  if(j < nw){
    float m = (float)(wsum[j] / (double)cnt.c[j]);
    m = fmaxf(m, 1e-5f);
    wscale[j] = m;          // = 1/s  (multiplied into GEMM output)
    wrecip[j] = 1.f/m;      // = s    (used for ternarization)
  }
}

// ---------- weight ternarize -> bf16 {-1,0,1} ----------
__global__ void k_wquant(const float* __restrict__ w, const float* __restrict__ srec,
                         u16* __restrict__ outq, size_t n4){
  size_t i = (size_t)blockIdx.x*256+threadIdx.x;
  if(i >= n4) return;
  float s = *srec;
  float4 v = ((const float4*)w)[i];
  float a0 = fminf(fmaxf(rintf(v.x*s),-1.f),1.f);
  float a1 = fminf(fmaxf(rintf(v.y*s),-1.f),1.f);
  float a2 = fminf(fmaxf(rintf(v.z*s),-1.f),1.f);
  float a3 = fminf(fmaxf(rintf(v.w*s),-1.f),1.f);
  u32 p0 = (u32)f2bf(a0) | ((u32)f2bf(a1)<<16);
  u32 p1 = (u32)f2bf(a2) | ((u32)f2bf(a3)<<16);
  ((uint2*)outq)[i] = make_uint2(p0,p1);
}

// ---------- activation RMS + act-quant (optional silu / modulate pre-transform) ----------
// out: bf16 integers in [-128,127]; rowsc[r] = clip(amax,1e-5)/127  (= 1/s)
__global__ void k_quant(const float* __restrict__ in, int ld, int K, int rpb,
                        const float* __restrict__ msh, const float* __restrict__ msc,
                        int do_silu,
                        u16* __restrict__ outq, float* __restrict__ rowsc){
  __shared__ float xr[2816];
  __shared__ float red[8];
  int r = blockIdx.x;
  const float* src = in + (size_t)r*ld;
  int b = r / rpb;
  float ss = 0.f, am = 0.f;
  for(int k=threadIdx.x; k<K; k+=256){
    float x = src[k];
    if(do_silu) x = x / (1.f + __expf(-x));
    if(msh) x = x*(1.f + msc[(size_t)b*6144 + k]) + msh[(size_t)b*6144 + k];
    xr[k] = x;
    ss += x*x; am = fmaxf(am, fabsf(x));
  }
  ss = wred_sum(ss); am = wred_max(am);
  if((threadIdx.x&63)==0){ red[threadIdx.x>>6]=ss; red[4+(threadIdx.x>>6)]=am; }
  __syncthreads();
  ss = red[0]+red[1]+red[2]+red[3];
  am = fmaxf(fmaxf(red[4],red[5]),fmaxf(red[6],red[7]));
  float rinv = 1.f / sqrtf(ss/(float)K + 1e-6f);
  float amn = fmaxf(am*rinv, 1e-5f);
  float s = 127.f/amn;
  if(threadIdx.x==0) rowsc[r] = amn/127.f;
  for(int k=threadIdx.x; k<K; k+=256){
    float xn = xr[k]*rinv;
    float q = rintf(xn*s);
    q = fminf(fmaxf(q,-128.f),127.f);
    outq[(size_t)r*K + k] = f2bf(q);
  }
}

// ---------- layernorm ----------
__global__ void k_ln(const float* __restrict__ in, const float* __restrict__ g,
                     const float* __restrict__ bt, float* __restrict__ outp){
  __shared__ float xr[1024];
  __shared__ float red[4];
  int r = blockIdx.x;
  const float* src = in + (size_t)r*1024;
  float s1 = 0.f;
  for(int k=threadIdx.x;k<1024;k+=256){ float x=src[k]; xr[k]=x; s1+=x; }
  s1 = wred_sum(s1);
  if((threadIdx.x&63)==0) red[threadIdx.x>>6]=s1;
  __syncthreads();
  float m = (red[0]+red[1]+red[2]+red[3])*(1.f/1024.f);
  float s2 = 0.f;
  for(int k=threadIdx.x;k<1024;k+=256){ float d=xr[k]-m; s2+=d*d; }
  s2 = wred_sum(s2);
  __syncthreads();
  if((threadIdx.x&63)==0) red[threadIdx.x>>6]=s2;
  __syncthreads();
  float v = (red[0]+red[1]+red[2]+red[3])*(1.f/1024.f);
  float rstd = rsqrtf(v + 1e-5f);
  for(int k=threadIdx.x;k<1024;k+=256)
    outp[(size_t)r*1024+k] = (xr[k]-m)*rstd*g[k] + bt[k];
}

__global__ void k_copy(const float* __restrict__ in, float* __restrict__ out, size_t n4){
  size_t i = (size_t)blockIdx.x*256+threadIdx.x;
  if(i<n4) ((float4*)out)[i] = ((const float4*)in)[i];
}

// ---------- main bitlinear GEMM: Y = (Aq int) @ (Wq tern)^T  * arow[r]*wscale ----------
// mode 0: store   mode 1: store + bias[c]   mode 2: out += gate[(r/rpb)*6144+c]*v
__global__ __launch_bounds__(256) void k_gemm(
    const u16* __restrict__ Aq, const float* __restrict__ arow,
    const u16* __restrict__ Wq, const float* __restrict__ wsc,
    int M, int N, int K, int mode,
    const float* __restrict__ bias, const float* __restrict__ gate,
    int rpb, float* __restrict__ out){
  __shared__ __align__(16) u16 As[128*64];
  __shared__ __align__(16) u16 Bs[128*64];
  int tid = threadIdx.x;
  int lane = tid & 63;
  int w = tid >> 6;
  int tn = blockIdx.x * 128;
  int tm = blockIdx.y * 128;
  int wr = (w>>1)*64, wc = (w&1)*64;
  f32x4 acc[4][4];
  #pragma unroll
  for(int i=0;i<4;i++)
    #pragma unroll
    for(int j=0;j<4;j++) acc[i][j] = (f32x4){0.f,0.f,0.f,0.f};
  int lr = lane >> 3;
  int lk = (lane & 7) * 8;
  int nk = K >> 6;
  for(int kt=0; kt<nk; ++kt){
    __syncthreads();
    int k0 = kt*64 + lk;
    #pragma unroll
    for(int i=0;i<4;i++){
      int r = (i*4 + w)*8 + lr;
      int gr = tm + r; gr = gr < M ? gr : M-1;   // clamp for M=4 (ada) tile
      gload16(Aq + (size_t)gr*K + k0, (char*)As + (i*4+w)*1024);
      int gc = tn + r;                            // N always multiple of 128
      gload16(Wq + (size_t)gc*K + k0, (char*)Bs + (i*4+w)*1024);
    }
    asm volatile("s_waitcnt vmcnt(0)" ::: "memory");
    __syncthreads();
    #pragma unroll
    for(int kk=0;kk<2;kk++){
      bf8 af[4], bfr[4];
      int kc = kk*32 + ((lane>>4)<<3);
      #pragma unroll
      for(int i=0;i<4;i++){
        af[i]  = *(const bf8*)&As[(wr + i*16 + (lane&15))*64 + kc];
        bfr[i] = *(const bf8*)&Bs[(wc + i*16 + (lane&15))*64 + kc];
      }
      #pragma unroll
      for(int i=0;i<4;i++)
        #pragma unroll
        for(int j=0;j<4;j++)
          acc[i][j] = __builtin_amdgcn_mfma_f32_16x16x32_bf16(af[i], bfr[j], acc[i][j], 0,0,0);
    }
  }
  float wsv = *wsc;
  int r0 = (lane>>4)*4;
  int cc = lane & 15;
  #pragma unroll
  for(int i=0;i<4;i++){
    int rb = tm + wr + i*16 + r0;
    #pragma unroll
    for(int j=0;j<4;j++){
      int c = tn + wc + j*16 + cc;
      #pragma unroll
      for(int q=0;q<4;q++){
        int r = rb + q;
        if(r < M){
          float v = acc[i][j][q] * arow[r] * wsv;
          size_t oi = (size_t)r*N + c;
          if(mode == 0) out[oi] = v;
          else if(mode == 1) out[oi] = v + bias[c];
          else out[oi] += gate[(size_t)(r/rpb)*6144 + c] * v;
        }
      }
    }
  }
}

// ---------- low-rank path: T16 = XN @ la^T ----------
__global__ void k_a1(const float* __restrict__ xn, const float* __restrict__ la,
                     float* __restrict__ t16, int rows){
  int t = blockIdx.x*256 + threadIdx.x;
  int r = t >> 4, n = t & 15;
  if(r >= rows) return;
  const float4* a = (const float4*)(xn + (size_t)r*1024);
  const float4* b = (const float4*)(la + (size_t)n*1024);
  float s = 0.f;
  #pragma unroll 8
  for(int k=0;k<256;k++){
    float4 av=a[k], bv=b[k];
    s += av.x*bv.x + av.y*bv.y + av.z*bv.z + av.w*bv.w;
  }
  t16[(size_t)r*16 + n] = s;
}

// q += mag[h] * (T16 @ lb^T)
__global__ void k_qadd(float* __restrict__ qkv, const float* __restrict__ t16,
                       const float* __restrict__ lb, const float* __restrict__ mag){
  int c = blockIdx.x*256 + threadIdx.x;  // 0..1023
  int r = blockIdx.y;
  const float4* a = (const float4*)(t16 + (size_t)r*16);
  const float4* b = (const float4*)(lb + (size_t)c*16);
  float s = 0.f;
  #pragma unroll
  for(int k=0;k<4;k++){ float4 av=a[k], bv=b[k]; s += av.x*bv.x+av.y*bv.y+av.z*bv.z+av.w*bv.w; }
  qkv[(size_t)r*3072 + c] += mag[c>>6]*s;
}

// ---------- fp32 flash attention over qkv buffer [(b*Nt+n)*3072 + {0,1024,2048}+h*64+d] ----------
__global__ __launch_bounds__(256) void k_attn(const float* __restrict__ qkv,
                                              float* __restrict__ outp, int Nt){
  __shared__ float qs[64][65];
  __shared__ float ks[64][65];   // reused as P after scores consumed
  __shared__ float vs[64][65];
  int b = blockIdx.z, h = blockIdx.y, q0 = blockIdx.x*64;
  int tid = threadIdx.x, tx = tid&15, ty = tid>>4;
  size_t base = ((size_t)b*Nt)*3072 + (size_t)h*64;
  for(int idx=tid; idx<64*64; idx+=256){
    int r = idx>>6, d = idx&63;
    qs[r][d] = qkv[base + (size_t)(q0+r)*3072 + d];
  }
  float m_[4], l_[4], o_[4][4];
  #pragma unroll
  for(int i=0;i<4;i++){ m_[i]=-1e30f; l_[i]=0.f;
    #pragma unroll
    for(int j=0;j<4;j++) o_[i][j]=0.f; }
  __syncthreads();
  for(int kt=0; kt<Nt; kt+=64){
    for(int idx=tid; idx<64*64; idx+=256){
      int r = idx>>6, d = idx&63;
      ks[r][d] = qkv[base + (size_t)(kt+r)*3072 + 1024 + d];
      vs[r][d] = qkv[base + (size_t)(kt+r)*3072 + 2048 + d];
    }
    __syncthreads();
    float s_[4][4];
    #pragma unroll
    for(int i=0;i<4;i++)
      #pragma unroll
      for(int j=0;j<4;j++) s_[i][j]=0.f;
    for(int kd=0; kd<64; kd++){
      float qv[4], kv[4];
      #pragma unroll
      for(int i=0;i<4;i++) qv[i]=qs[ty+16*i][kd];
      #pragma unroll
      for(int j=0;j<4;j++) kv[j]=ks[tx+16*j][kd];
      #pragma unroll
      for(int i=0;i<4;i++)
        #pragma unroll
        for(int j=0;j<4;j++) s_[i][j] += qv[i]*kv[j];
    }
    __syncthreads();   // everyone done reading ks -> safe to overwrite with P
    #pragma unroll
    for(int i=0;i<4;i++){
      float tm = -1e30f;
      #pragma unroll
      for(int j=0;j<4;j++){ s_[i][j]*=0.125f; tm = fmaxf(tm, s_[i][j]); }
      #pragma unroll
      for(int mk=8;mk;mk>>=1) tm = fmaxf(tm, __shfl_xor(tm, mk));
      float mn = fmaxf(m_[i], tm);
      float resc = __expf(m_[i]-mn);
      float psum = 0.f;
      #pragma unroll
      for(int j=0;j<4;j++){ float p=__expf(s_[i][j]-mn); s_[i][j]=p; psum+=p; }
      #pragma unroll
      for(int mk=8;mk;mk>>=1) psum += __shfl_xor(psum, mk);
      l_[i] = l_[i]*resc + psum;
      m_[i] = mn;
      #pragma unroll
      for(int j=0;j<4;j++){ o_[i][j]*=resc; ks[ty+16*i][tx+16*j]=s_[i][j]; }
    }
    __syncthreads();
    for(int kd=0; kd<64; kd++){
      float pv[4], vv[4];
      #pragma unroll
      for(int i=0;i<4;i++) pv[i]=ks[ty+16*i][kd];
      #pragma unroll
      for(int j=0;j<4;j++) vv[j]=vs[kd][tx+16*j];
      #pragma unroll
      for(int i=0;i<4;i++)
        #pragma unroll
        for(int j=0;j<4;j++) o_[i][j] += pv[i]*vv[j];
    }
    __syncthreads();
  }
  #pragma unroll
  for(int i=0;i<4;i++){
    float inv = 1.f/l_[i];
    int r = q0 + ty + 16*i;
    #pragma unroll
    for(int j=0;j<4;j++)
      outp[((size_t)b*Nt + r)*1024 + (size_t)h*64 + tx + 16*j] = o_[i][j]*inv;
  }
}

// ---------- HGRN gates + scan ----------
__global__ void k_gatei(float* __restrict__ bi, float* __restrict__ bf, int n){
  int i = blockIdx.x*256 + threadIdx.x;
  if(i >= n) return;
  float f = 1.f/(1.f+__expf(-bf[i]));
  float x = bi[i];
  float si = x/(1.f+__expf(-x));
  bi[i] = si*(1.f-f);
  bf[i] = f;
}
__global__ void k_scan1(const float* __restrict__ iin, const float* __restrict__ fin,
                        float* __restrict__ Fo, float* __restrict__ Ho, int Nt, int L){
  int c = blockIdx.x*256 + threadIdx.x;
  int ch = blockIdx.y, b = blockIdx.z;
  float h = 0.f, F = 1.f;
  size_t base = ((size_t)b*Nt + (size_t)ch*L)*DD + c;
  for(int t=0;t<L;t++){
    float ft = fin[base + (size_t)t*DD];
    float it = iin[base + (size_t)t*DD];
    h = ft*h + it; F *= ft;
  }
  int CH = Nt/L;
  size_t o = ((size_t)b*CH + ch)*DD + c;
  Fo[o]=F; Ho[o]=h;
}
__global__ void k_scan2(const float* __restrict__ Fo, const float* __restrict__ Ho,
                        float* __restrict__ carry, int CH){
  int id = blockIdx.x*256 + threadIdx.x;   // 4096
  int b = id>>10, c = id&1023;
  float h = 0.f;
  for(int ch=0; ch<CH; ch++){
    size_t o = ((size_t)b*CH + ch)*DD + c;
    carry[o] = h;
    h = Fo[o]*h + Ho[o];
  }
}
__global__ void k_scan3(const float* __restrict__ iin, const float* __restrict__ fin,
                        const float* __restrict__ carry, float* __restrict__ oo, int Nt, int L){
  int c = blockIdx.x*256 + threadIdx.x;
  int ch = blockIdx.y, b = blockIdx.z;
  int CH = Nt/L;
  float h = carry[((size_t)b*CH + ch)*DD + c];
  size_t base = ((size_t)b*Nt + (size_t)ch*L)*DD + c;
  for(int t=0;t<L;t++){
    float ft = fin[base + (size_t)t*DD];
    float it = iin[base + (size_t)t*DD];
    h = ft*h + it;
    oo[base + (size_t)t*DD] = h;
  }
}
// o' = rms(o)*gn*g*sigmoid(g)
__global__ void k_oprime(const float* __restrict__ o, const float* __restrict__ g,
                         const float* __restrict__ gn, float* __restrict__ outp){
  __shared__ float red[4];
  int r = blockIdx.x;
  float ss = 0.f;
  for(int k=threadIdx.x;k<1024;k+=256){ float v=o[(size_t)r*1024+k]; ss += v*v; }
  ss = wred_sum(ss);
  if((threadIdx.x&63)==0) red[threadIdx.x>>6]=ss;
  __syncthreads();
  float tot = red[0]+red[1]+red[2]+red[3];
  float rinv = 1.f/sqrtf(tot*(1.f/1024.f) + 1e-6f);
  for(int k=threadIdx.x;k<1024;k+=256){
    float gv = g[(size_t)r*1024+k];
    float sig = 1.f/(1.f+__expf(-gv));
    outp[(size_t)r*1024+k] = o[(size_t)r*1024+k]*rinv*gn[k]*gv*sig;
  }
}

// swiglu in place: Y[r, c] = silu(Y[r,c]) * Y[r, 2816+c]
__global__ void k_swiglu(float* __restrict__ Y){
  int c = blockIdx.x*256 + threadIdx.x;   // grid.x = 11 -> 2816
  int r = blockIdx.y;
  float g = Y[(size_t)r*5632 + c];
  float y = Y[(size_t)r*5632 + 2816 + c];
  float si = g/(1.f+__expf(-g));
  Y[(size_t)r*5632 + c] = si*y;
}

// =====================================================================
extern "C" void kernel_launch(void* const* d_in, const int* in_sizes, int n_in,
                              void* d_out, int out_size, void* d_ws, size_t ws_size,
                              hipStream_t stream){
  const float* X     = (const float*)d_in[0];
  const float* Y     = (const float*)d_in[1];
  const float* C     = (const float*)d_in[2];
  const float* ADA_W = (const float*)d_in[3];
  const float* ADA_B = (const float*)d_in[4];
  const float* LNX_G = (const float*)d_in[5];
  const float* LNX_B = (const float*)d_in[6];
  const float* LNY_G = (const float*)d_in[7];
  const float* LNY_B = (const float*)d_in[8];
  const float* CAX_WQKV=(const float*)d_in[9];
  const float* CAX_MAG =(const float*)d_in[10];
  const float* CAX_LA  =(const float*)d_in[11];
  const float* CAX_LB  =(const float*)d_in[12];
  const float* CAX_WP  =(const float*)d_in[13];
  const float* CAY_WQKV=(const float*)d_in[14];
  const float* CAY_MAG =(const float*)d_in[15];
  const float* CAY_LA  =(const float*)d_in[16];
  const float* CAY_LB  =(const float*)d_in[17];
  const float* CAY_WP  =(const float*)d_in[18];
  const float* AX_WI = (const float*)d_in[19];
  const float* AX_WF = (const float*)d_in[20];
  const float* AX_WG = (const float*)d_in[21];
  const float* AX_WO = (const float*)d_in[22];
  const float* AX_GN = (const float*)d_in[23];
  const float* AY_WI = (const float*)d_in[24];
  const float* AY_WF = (const float*)d_in[25];
  const float* AY_WG = (const float*)d_in[26];
  const float* AY_WO = (const float*)d_in[27];
  const float* AY_GN = (const float*)d_in[28];
  const float* MX_WG = (const float*)d_in[29];
  const float* MX_WD = (const float*)d_in[30];
  const float* MY_WG = (const float*)d_in[31];
  const float* MY_WD = (const float*)d_in[32];

  float* OUTX = (float*)d_out;
  float* OUTY = OUTX + (size_t)4096*1024;

  // ---- workspace layout ----
  char* base = (char*)d_ws;
  size_t cur = 0;
  auto alloc = [&](size_t bytes)->char*{
    char* p = base + cur; cur += (bytes + 255) & ~(size_t)255; return p; };
  double* WSUM  = (double*)alloc(32*sizeof(double));
  float* WSCALE = (float*)alloc(32*sizeof(float));
  float* WRECIP = (float*)alloc(32*sizeof(float));
  float* MOD    = (float*)alloc((size_t)4*6144*4);
  float* AROW   = (float*)alloc((size_t)4096*4);
  u16*   WQ     = (u16*)alloc((size_t)40370176*2);
  u16*   AQ     = (u16*)alloc((size_t)4096*2816*2);
  float* XN     = (float*)alloc((size_t)4096*1024*4);
  float* YN     = (float*)alloc((size_t)1024*1024*4);
  float* BUFA   = (float*)alloc((size_t)4096*5632*4);
  float* BUFE   = (float*)alloc((size_t)4096*1024*4);
  float* BUFF   = (float*)alloc((size_t)4096*1024*4);
  float* T16    = (float*)alloc((size_t)4096*16*4);
  float* SCF    = (float*)alloc((size_t)4*16*1024*4);
  float* SCH    = (float*)alloc((size_t)4*16*1024*4);
  float* SCC    = (float*)alloc((size_t)4*16*1024*4);
  (void)ws_size; (void)in_sizes; (void)n_in; (void)out_size;

  // ---- weight table (order defines slot index) ----
  const float* wptr[17] = {ADA_W, CAX_WQKV, CAX_WP, CAY_WQKV, CAY_WP,
                           AX_WI, AX_WF, AX_WG, AX_WO,
                           AY_WI, AY_WF, AY_WG, AY_WO,
                           MX_WG, MX_WD, MY_WG, MY_WD};
  const size_t wn[17] = {6291456,3145728,1048576,3145728,1048576,
                         1048576,1048576,1048576,1048576,
                         1048576,1048576,1048576,1048576,
                         5767168,2883584,5767168,2883584};
  size_t woff[17]; { size_t o=0; for(int j=0;j<17;j++){ woff[j]=o; o+=wn[j]; } }

  hipMemsetAsync(WSUM, 0, 17*sizeof(double), stream);
  for(int j=0;j<17;j++){
    size_t n4 = wn[j]/4;
    int blocks = (int)((n4+255)/256); if(blocks>768) blocks=768;
    k_wabs<<<blocks,256,0,stream>>>(wptr[j], n4, WSUM+j);
  }
  Counts cnt; for(int j=0;j<17;j++) cnt.c[j] = (float)wn[j];
  k_wfin<<<1,32,0,stream>>>(WSUM, WSCALE, WRECIP, cnt, 17);
  for(int j=0;j<17;j++){
    size_t n4 = wn[j]/4;
    k_wquant<<<(int)((n4+255)/256),256,0,stream>>>(wptr[j], WRECIP+j, WQ+woff[j], n4);
  }

  auto gemm = [&](int slot, const u16* aq, int M, int N, int K, int mode,
                  const float* bias, const float* gate, int rpb, float* out){
    k_gemm<<<dim3(N/128,(M+127)/128),256,0,stream>>>(aq, AROW, WQ+woff[slot],
        WSCALE+slot, M, N, K, mode, bias, gate, rpb, out);
  };

  // ---- mod = bitlinear(silu(c), ada_w, ada_b) ----
  k_quant<<<4,256,0,stream>>>(C, 1024, 1024, 1, nullptr, nullptr, 1, AQ, AROW);
  gemm(0, AQ, 4, 6144, 1024, 1, ADA_B, nullptr, 1, MOD);

  // ---- layernorms + residual init ----
  k_ln<<<4096,256,0,stream>>>(X, LNX_G, LNX_B, XN);
  k_ln<<<1024,256,0,stream>>>(Y, LNY_G, LNY_B, YN);
  k_copy<<<4096,256,0,stream>>>(X, OUTX, (size_t)1048576);
  k_copy<<<1024,256,0,stream>>>(Y, OUTY, (size_t)262144);

  const float* G1 = MOD + 2048;   // gate_msa
  const float* G2 = MOD + 5120;   // gate_mlp

  // ---- dora attn x ----
  k_quant<<<4096,256,0,stream>>>(XN, 1024, 1024, 1024, nullptr, nullptr, 0, AQ, AROW);
  gemm(1, AQ, 4096, 3072, 1024, 0, nullptr, nullptr, 1, BUFA);
  k_a1<<<256,256,0,stream>>>(XN, CAX_LA, T16, 4096);
  k_qadd<<<dim3(4,4096),256,0,stream>>>(BUFA, T16, CAX_LB, CAX_MAG);
  k_attn<<<dim3(16,16,4),256,0,stream>>>(BUFA, BUFF, 1024);
  k_quant<<<4096,256,0,stream>>>(BUFF, 1024, 1024, 1024, nullptr, nullptr, 0, AQ, AROW);
  gemm(2, AQ, 4096, 1024, 1024, 2, nullptr, G1, 1024, OUTX);

  // ---- dora attn y ----
  k_quant<<<1024,256,0,stream>>>(YN, 1024, 1024, 256, nullptr, nullptr, 0, AQ, AROW);
  gemm(3, AQ, 1024, 3072, 1024, 0, nullptr, nullptr, 1, BUFA);
  k_a1<<<64,256,0,stream>>>(YN, CAY_LA, T16, 1024);
  k_qadd<<<dim3(4,1024),256,0,stream>>>(BUFA, T16, CAY_LB, CAY_MAG);
  k_attn<<<dim3(4,16,4),256,0,stream>>>(BUFA, BUFF, 256);
  k_quant<<<1024,256,0,stream>>>(BUFF, 1024, 1024, 256, nullptr, nullptr, 0, AQ, AROW);
  gemm(4, AQ, 1024, 1024, 1024, 2, nullptr, G1, 256, OUTY);

  // ---- hgrn x ----
  float* BI = BUFA;
  float* BF = BUFA + (size_t)4096*1024;
  float* BG = BUFA + (size_t)8192*1024;
  k_quant<<<4096,256,0,stream>>>(XN, 1024, 1024, 1024, MOD, MOD+1024, 0, AQ, AROW);
  gemm(5, AQ, 4096, 1024, 1024, 0, nullptr, nullptr, 1, BI);
  gemm(6, AQ, 4096, 1024, 1024, 0, nullptr, nullptr, 1, BF);
  gemm(7, AQ, 4096, 1024, 1024, 0, nullptr, nullptr, 1, BG);
  k_gatei<<<16384,256,0,stream>>>(BI, BF, 4194304);
  k_scan1<<<dim3(4,16,4),256,0,stream>>>(BI, BF, SCF, SCH, 1024, 64);
  k_scan2<<<16,256,0,stream>>>(SCF, SCH, SCC, 16);
  k_scan3<<<dim3(4,16,4),256,0,stream>>>(BI, BF, SCC, BUFE, 1024, 64);
  k_oprime<<<4096,256,0,stream>>>(BUFE, BG, AX_GN, BUFF);
  k_quant<<<4096,256,0,stream>>>(BUFF, 1024, 1024, 1024, nullptr, nullptr, 0, AQ, AROW);
  gemm(8, AQ, 4096, 1024, 1024, 2, nullptr, G1, 1024, OUTX);

  // ---- hgrn y ----
  k_quant<<<1024,256,0,stream>>>(YN, 1024, 1024, 256, MOD, MOD+1024, 0, AQ, AROW);
  gemm(9,  AQ, 1024, 1024, 1024, 0, nullptr, nullptr, 1, BI);
  gemm(10, AQ, 1024, 1024, 1024, 0, nullptr, nullptr, 1, BF);
  gemm(11, AQ, 1024, 1024, 1024, 0, nullptr, nullptr, 1, BG);
  k_gatei<<<4096,256,0,stream>>>(BI, BF, 1048576);
  k_scan1<<<dim3(4,16,4),256,0,stream>>>(BI, BF, SCF, SCH, 256, 16);
  k_scan2<<<16,256,0,stream>>>(SCF, SCH, SCC, 16);
  k_scan3<<<dim3(4,16,4),256,0,stream>>>(BI, BF, SCC, BUFE, 256, 16);
  k_oprime<<<1024,256,0,stream>>>(BUFE, BG, AY_GN, BUFF);
  k_quant<<<1024,256,0,stream>>>(BUFF, 1024, 1024, 256, nullptr, nullptr, 0, AQ, AROW);
  gemm(12, AQ, 1024, 1024, 1024, 2, nullptr, G1, 256, OUTY);

  // ---- mlp x ----
  k_ln<<<4096,256,0,stream>>>(OUTX, LNX_G, LNX_B, XN);
  k_quant<<<4096,256,0,stream>>>(XN, 1024, 1024, 1024, MOD+3072, MOD+4096, 0, AQ, AROW);
  gemm(13, AQ, 4096, 5632, 1024, 0, nullptr, nullptr, 1, BUFA);
  k_swiglu<<<dim3(11,4096),256,0,stream>>>(BUFA);
  k_quant<<<4096,256,0,stream>>>(BUFA, 5632, 2816, 1024, nullptr, nullptr, 0, AQ, AROW);
  gemm(14, AQ, 4096, 1024, 2816, 2, nullptr, G2, 1024, OUTX);

  // ---- mlp y ----
  k_ln<<<1024,256,0,stream>>>(OUTY, LNY_G, LNY_B, YN);
  k_quant<<<1024,256,0,stream>>>(YN, 1024, 1024, 256, MOD+3072, MOD+4096, 0, AQ, AROW);
  gemm(15, AQ, 1024, 5632, 1024, 0, nullptr, nullptr, 1, BUFA);
  k_swiglu<<<dim3(11,1024),256,0,stream>>>(BUFA);
  k_quant<<<1024,256,0,stream>>>(BUFA, 5632, 2816, 256, nullptr, nullptr, 0, AQ, AROW);
  gemm(16, AQ, 1024, 1024, 2816, 2, nullptr, G2, 256, OUTY);
}

// Round 2
// 1662.376 us; speedup vs baseline: 1.3292x; 1.3292x over previous
//
#include <hip/hip_runtime.h>

typedef unsigned short u16;
typedef unsigned int u32;
typedef __bf16 bf8 __attribute__((ext_vector_type(8)));
typedef float f32x4 __attribute__((ext_vector_type(4)));

#define DD 1024

// ---------- helpers ----------
__device__ __forceinline__ u16 f2bf(float x){
  u32 u = __float_as_uint(x);
  u += 0x7fff + ((u >> 16) & 1);
  return (u16)(u >> 16);
}
__device__ __forceinline__ float wred_sum(float v){
  #pragma unroll
  for(int m=32;m;m>>=1) v += __shfl_xor(v,m);
  return v;
}
__device__ __forceinline__ float wred_max(float v){
  #pragma unroll
  for(int m=32;m;m>>=1) v = fmaxf(v,__shfl_xor(v,m));
  return v;
}
__device__ __forceinline__ double wred_sum_d(double v){
  #pragma unroll
  for(int m=32;m;m>>=1) v += __shfl_xor(v,m);
  return v;
}
__device__ __forceinline__ void gload16(const void* g, void* l){
  __builtin_amdgcn_global_load_lds(
      (const __attribute__((address_space(1))) u32*)g,
      (__attribute__((address_space(3))) u32*)l, 16, 0, 0);
}

// ---------- batched weight scale: sum |w| (f64 accum) ----------
struct WT { const float* p[17]; u32 n4[17]; u32 off4[17]; };

__global__ void k_wabs_all(WT wt, double* __restrict__ wsum){
  int j = blockIdx.y;
  const float4* w = (const float4*)wt.p[j];
  u32 n4 = wt.n4[j];
  double s = 0.0;
  for(u32 i=blockIdx.x*256+threadIdx.x; i<n4; i+=gridDim.x*256){
    float4 v = w[i];
    s += (double)(fabsf(v.x)+fabsf(v.y)) + (double)(fabsf(v.z)+fabsf(v.w));
  }
  s = wred_sum_d(s);
  __shared__ double red[4];
  if((threadIdx.x&63)==0) red[threadIdx.x>>6]=s;
  __syncthreads();
  if(threadIdx.x==0) atomicAdd(wsum+j, red[0]+red[1]+red[2]+red[3]);
}

struct Counts{ float c[17]; };
__global__ void k_wfin(const double* __restrict__ wsum, float* __restrict__ wscale,
                       float* __restrict__ wrecip, Counts cnt, int nw){
  int j = threadIdx.x;
  if(j < nw){
    float m = (float)(wsum[j] / (double)cnt.c[j]);
    m = fmaxf(m, 1e-5f);
    wscale[j] = m;          // = 1/s  (multiplied into GEMM output)
    wrecip[j] = 1.f/m;      // = s    (used for ternarization)
  }
}

// ---------- batched weight ternarize -> bf16 {-1,0,1} ----------
__global__ void k_wquant_all(WT wt, const float* __restrict__ wrecip, u16* __restrict__ wq){
  int j = blockIdx.y;
  const float4* w = (const float4*)wt.p[j];
  uint2* outq = (uint2*)(wq + 4ull*wt.off4[j]);
  u32 n4 = wt.n4[j];
  float s = wrecip[j];
  for(u32 i=blockIdx.x*256+threadIdx.x; i<n4; i+=gridDim.x*256){
    float4 v = w[i];
    float a0 = fminf(fmaxf(rintf(v.x*s),-1.f),1.f);
    float a1 = fminf(fmaxf(rintf(v.y*s),-1.f),1.f);
    float a2 = fminf(fmaxf(rintf(v.z*s),-1.f),1.f);
    float a3 = fminf(fmaxf(rintf(v.w*s),-1.f),1.f);
    u32 p0 = (u32)f2bf(a0) | ((u32)f2bf(a1)<<16);
    u32 p1 = (u32)f2bf(a2) | ((u32)f2bf(a3)<<16);
    outq[i] = make_uint2(p0,p1);
  }
}

// ---------- activation RMS + act-quant ----------
// mode 0: plain (+optional modulate)  mode 1: silu(x)  mode 2: swiglu pair silu(x[k])*x[k+K]
__global__ void k_quant(const float* __restrict__ in, int ld, int K, int rpb,
                        const float* __restrict__ msh, const float* __restrict__ msc,
                        int mode,
                        u16* __restrict__ outq, float* __restrict__ rowsc){
  __shared__ float xr[2816];
  __shared__ float red[8];
  int r = blockIdx.x;
  const float* src = in + (size_t)r*ld;
  int b = r / rpb;
  float ss = 0.f, am = 0.f;
  for(int k=threadIdx.x; k<K; k+=256){
    float x = src[k];
    if(mode==1) x = x / (1.f + __expf(-x));
    else if(mode==2){ float yv = src[k+K]; x = (x/(1.f+__expf(-x)))*yv; }
    if(msh) x = x*(1.f + msc[(size_t)b*6144 + k]) + msh[(size_t)b*6144 + k];
    xr[k] = x;
    ss += x*x; am = fmaxf(am, fabsf(x));
  }
  ss = wred_sum(ss); am = wred_max(am);
  if((threadIdx.x&63)==0){ red[threadIdx.x>>6]=ss; red[4+(threadIdx.x>>6)]=am; }
  __syncthreads();
  ss = red[0]+red[1]+red[2]+red[3];
  am = fmaxf(fmaxf(red[4],red[5]),fmaxf(red[6],red[7]));
  float rinv = 1.f / sqrtf(ss/(float)K + 1e-6f);
  float amn = fmaxf(am*rinv, 1e-5f);
  float s = 127.f/amn;
  if(threadIdx.x==0) rowsc[r] = amn/127.f;
  for(int k=threadIdx.x; k<K; k+=256){
    float xn = xr[k]*rinv;
    float q = rintf(xn*s);
    q = fminf(fmaxf(q,-128.f),127.f);
    outq[(size_t)r*K + k] = f2bf(q);
  }
}

// ---------- layernorm ----------
__global__ void k_ln(const float* __restrict__ in, const float* __restrict__ g,
                     const float* __restrict__ bt, float* __restrict__ outp){
  __shared__ float xr[1024];
  __shared__ float red[4];
  int r = blockIdx.x;
  const float* src = in + (size_t)r*1024;
  float s1 = 0.f;
  for(int k=threadIdx.x;k<1024;k+=256){ float x=src[k]; xr[k]=x; s1+=x; }
  s1 = wred_sum(s1);
  if((threadIdx.x&63)==0) red[threadIdx.x>>6]=s1;
  __syncthreads();
  float m = (red[0]+red[1]+red[2]+red[3])*(1.f/1024.f);
  float s2 = 0.f;
  for(int k=threadIdx.x;k<1024;k+=256){ float d=xr[k]-m; s2+=d*d; }
  s2 = wred_sum(s2);
  __syncthreads();
  if((threadIdx.x&63)==0) red[threadIdx.x>>6]=s2;
  __syncthreads();
  float v = (red[0]+red[1]+red[2]+red[3])*(1.f/1024.f);
  float rstd = rsqrtf(v + 1e-5f);
  for(int k=threadIdx.x;k<1024;k+=256)
    outp[(size_t)r*1024+k] = (xr[k]-m)*rstd*g[k] + bt[k];
}

__global__ void k_copy(const float* __restrict__ in, float* __restrict__ out, size_t n4){
  size_t i = (size_t)blockIdx.x*256+threadIdx.x;
  if(i<n4) ((float4*)out)[i] = ((const float4*)in)[i];
}

// ---------- main bitlinear GEMM ----------
// mode 0: store   mode 1: store + bias[c]   mode 2: out += gate*v
// mode 3: qkv pack -> bf16 Qb/Kb/Vb head-major, Q gets low-rank delta
__global__ __launch_bounds__(256) void k_gemm(
    const u16* __restrict__ Aq, const float* __restrict__ arow,
    const u16* __restrict__ Wq, const float* __restrict__ wsc, int wshift,
    int M, int N, int K, int mode, int ntshift,
    const float* __restrict__ bias, const float* __restrict__ gate,
    const float* __restrict__ t16, const float* __restrict__ lb,
    const float* __restrict__ mag,
    u16* __restrict__ qb, u16* __restrict__ kb, u16* __restrict__ vb,
    float* __restrict__ out){
  __shared__ __align__(16) u16 As[128*64];
  __shared__ __align__(16) u16 Bs[128*64];
  int tid = threadIdx.x;
  int lane = tid & 63;
  int w = tid >> 6;
  // bijective XCD swizzle + column-major tile order (weight strip stays L2-hot)
  int gy = (M+127)>>7;
  int nwg = gridDim.x;
  int q8 = nwg>>3, r8 = nwg&7;
  int xcd = blockIdx.x&7, off8 = blockIdx.x>>3;
  int tile = (xcd<r8 ? xcd*(q8+1) : r8*(q8+1) + (xcd-r8)*q8) + off8;
  int tn = (tile/gy)*128;
  int tm = (tile%gy)*128;
  int wr = (w>>1)*64, wc = (w&1)*64;
  f32x4 acc[4][4];
  #pragma unroll
  for(int i=0;i<4;i++)
    #pragma unroll
    for(int j=0;j<4;j++) acc[i][j] = (f32x4){0.f,0.f,0.f,0.f};
  int lr = lane >> 3;
  int lk = (lane & 7) * 8;
  int nk = K >> 6;
  for(int kt=0; kt<nk; ++kt){
    __syncthreads();
    int k0 = kt*64 + lk;
    #pragma unroll
    for(int i=0;i<4;i++){
      int r = (i*4 + w)*8 + lr;
      int gr = tm + r; gr = gr < M ? gr : M-1;   // clamp for M=4 (ada) tile
      gload16(Aq + (size_t)gr*K + k0, (char*)As + (i*4+w)*1024);
      int gc = tn + r;                            // N always multiple of 128
      gload16(Wq + (size_t)gc*K + k0, (char*)Bs + (i*4+w)*1024);
    }
    asm volatile("s_waitcnt vmcnt(0)" ::: "memory");
    __syncthreads();
    #pragma unroll
    for(int kk=0;kk<2;kk++){
      bf8 af[4], bfr[4];
      int kc = kk*32 + ((lane>>4)<<3);
      #pragma unroll
      for(int i=0;i<4;i++){
        af[i]  = *(const bf8*)&As[(wr + i*16 + (lane&15))*64 + kc];
        bfr[i] = *(const bf8*)&Bs[(wc + i*16 + (lane&15))*64 + kc];
      }
      #pragma unroll
      for(int i=0;i<4;i++)
        #pragma unroll
        for(int j=0;j<4;j++)
          acc[i][j] = __builtin_amdgcn_mfma_f32_16x16x32_bf16(af[i], bfr[j], acc[i][j], 0,0,0);
    }
  }
  int r0 = (lane>>4)*4;
  int cc = lane & 15;
  int Nt = 1 << ntshift;
  #pragma unroll
  for(int i=0;i<4;i++){
    int rb = tm + wr + i*16 + r0;
    #pragma unroll
    for(int j=0;j<4;j++){
      int c = tn + wc + j*16 + cc;
      float wsv = wsc[c>>wshift];
      #pragma unroll
      for(int q=0;q<4;q++){
        int r = rb + q;
        if(r < M){
          float v = acc[i][j][q] * arow[r] * wsv;
          if(mode == 0) out[(size_t)r*N + c] = v;
          else if(mode == 1) out[(size_t)r*N + c] = v + bias[c];
          else if(mode == 2) out[(size_t)r*N + c] += gate[(size_t)(r>>ntshift)*6144 + c] * v;
          else {
            int which = c >> 10, c2 = c & 1023, h = c2 >> 6, d = c2 & 63;
            if(which == 0){
              const float4* tp = (const float4*)(t16 + (size_t)r*16);
              const float4* lp = (const float4*)(lb + (size_t)c2*16);
              float ds = 0.f;
              #pragma unroll
              for(int kk2=0;kk2<4;kk2++){
                float4 a4 = tp[kk2], b4 = lp[kk2];
                ds += a4.x*b4.x + a4.y*b4.y + a4.z*b4.z + a4.w*b4.w;
              }
              v += mag[h]*ds;
            }
            u16* dst = which==0 ? qb : (which==1 ? kb : vb);
            int b = r >> ntshift, n = r & (Nt-1);
            dst[((size_t)(b*16+h)*Nt + n)*64 + d] = f2bf(v);
          }
        }
      }
    }
  }
}

// ---------- low-rank path: T16 = XN @ la^T ----------
__global__ void k_a1(const float* __restrict__ xn, const float* __restrict__ la,
                     float* __restrict__ t16, int rows){
  int t = blockIdx.x*256 + threadIdx.x;
  int r = t >> 4, n = t & 15;
  if(r >= rows) return;
  const float4* a = (const float4*)(xn + (size_t)r*1024);
  const float4* b = (const float4*)(la + (size_t)n*1024);
  float s = 0.f;
  #pragma unroll 8
  for(int k=0;k<256;k++){
    float4 av=a[k], bv=b[k];
    s += av.x*bv.x + av.y*bv.y + av.z*bv.z + av.w*bv.w;
  }
  t16[(size_t)r*16 + n] = s;
}

// ---------- MFMA flash attention, bf16 Q/K/V head-major [bh][n][64] ----------
__global__ __launch_bounds__(256) void k_attn2(const u16* __restrict__ Qb,
    const u16* __restrict__ Kb, const u16* __restrict__ Vb,
    float* __restrict__ outp, int Nt){
  __shared__ __align__(16) u16 Ks[64*72];
  __shared__ __align__(16) u16 Vt[64*72];
  __shared__ __align__(16) u16 Ps[4*16*72];
  int tid = threadIdx.x, lane = tid&63, w = tid>>6;
  int bh = blockIdx.y;
  int q0 = blockIdx.x*64;
  size_t hb = (size_t)bh*Nt*64;
  bf8 qf[2];
  {
    const u16* qp = Qb + hb + (size_t)(q0 + w*16 + (lane&15))*64 + ((lane>>4)*8);
    qf[0] = *(const bf8*)qp;
    qf[1] = *(const bf8*)(qp+32);
  }
  float m_[4], l_[4];
  f32x4 o_[4];
  #pragma unroll
  for(int r=0;r<4;r++){ m_[r]=-1e30f; l_[r]=0.f; }
  #pragma unroll
  for(int t=0;t<4;t++) o_[t]=(f32x4){0.f,0.f,0.f,0.f};
  int ntiles = Nt >> 6;
  int sn = tid>>2, sc = tid&3;
  for(int kt=0; kt<ntiles; kt++){
    __syncthreads();
    {
      const u16* kg = Kb + hb + (size_t)(kt*64)*64;
      const u16* vg = Vb + hb + (size_t)(kt*64)*64;
      *(uint4*)&Ks[sn*72 + sc*8]      = *(const uint4*)&kg[sn*64 + sc*8];
      *(uint4*)&Ks[sn*72 + sc*8 + 32] = *(const uint4*)&kg[sn*64 + sc*8 + 32];
      uint4 v0 = *(const uint4*)&vg[sn*64 + sc*8];
      uint4 v1 = *(const uint4*)&vg[sn*64 + sc*8 + 32];
      const u16* e0 = (const u16*)&v0; const u16* e1 = (const u16*)&v1;
      #pragma unroll
      for(int j=0;j<8;j++){
        Vt[(sc*8+j)*72 + sn]    = e0[j];
        Vt[(sc*8+32+j)*72 + sn] = e1[j];
      }
    }
    __syncthreads();
    // S[16q][64k] per wave
    f32x4 s_[4];
    #pragma unroll
    for(int t=0;t<4;t++) s_[t]=(f32x4){0.f,0.f,0.f,0.f};
    #pragma unroll
    for(int c=0;c<2;c++){
      #pragma unroll
      for(int t=0;t<4;t++){
        bf8 kf = *(const bf8*)&Ks[(t*16 + (lane&15))*72 + (lane>>4)*8 + 32*c];
        s_[t] = __builtin_amdgcn_mfma_f32_16x16x32_bf16(qf[c], kf, s_[t], 0,0,0);
      }
    }
    // online softmax (state replicated over the 16 lanes of each group)
    #pragma unroll
    for(int r=0;r<4;r++){
      float mx = fmaxf(fmaxf(s_[0][r], s_[1][r]), fmaxf(s_[2][r], s_[3][r]));
      mx *= 0.125f;
      #pragma unroll
      for(int mk=1; mk<16; mk<<=1) mx = fmaxf(mx, __shfl_xor(mx, mk));
      float mn = fmaxf(m_[r], mx);
      float resc = __expf(m_[r] - mn);
      float ps = 0.f;
      #pragma unroll
      for(int t=0;t<4;t++){
        float p = __expf(s_[t][r]*0.125f - mn);
        Ps[w*1152 + ((lane>>4)*4 + r)*72 + (lane&15) + 16*t] = f2bf(p);
        ps += p;
      }
      #pragma unroll
      for(int mk=1; mk<16; mk<<=1) ps += __shfl_xor(ps, mk);
      l_[r] = l_[r]*resc + ps;
      m_[r] = mn;
      #pragma unroll
      for(int t=0;t<4;t++) o_[t][r] *= resc;
    }
    // PV: O[16q][64d] += P @ V
    #pragma unroll
    for(int c=0;c<2;c++){
      bf8 pf = *(const bf8*)&Ps[w*1152 + (lane&15)*72 + (lane>>4)*8 + 32*c];
      #pragma unroll
      for(int dt=0;dt<4;dt++){
        bf8 vf = *(const bf8*)&Vt[(dt*16 + (lane&15))*72 + (lane>>4)*8 + 32*c];
        o_[dt] = __builtin_amdgcn_mfma_f32_16x16x32_bf16(pf, vf, o_[dt], 0,0,0);
      }
    }
  }
  int b = bh >> 4, h = bh & 15;
  #pragma unroll
  for(int r=0;r<4;r++){
    float inv = 1.f/l_[r];
    int qrow = q0 + w*16 + (lane>>4)*4 + r;
    size_t ob = ((size_t)b*Nt + qrow)*1024 + (size_t)h*64;
    #pragma unroll
    for(int dt=0;dt<4;dt++)
      outp[ob + dt*16 + (lane&15)] = o_[dt][r]*inv;
  }
}

// ---------- HGRN gates + scan (i/f/g packed in rows of 3072) ----------
__global__ void k_gatei(float* __restrict__ qg, int n){
  int idx = blockIdx.x*256 + threadIdx.x;
  if(idx >= n) return;
  int r = idx >> 10, c = idx & 1023;
  size_t bi = (size_t)r*3072 + c;
  float f = 1.f/(1.f+__expf(-qg[bi+1024]));
  float x = qg[bi];
  float si = x/(1.f+__expf(-x));
  qg[bi] = si*(1.f-f);
  qg[bi+1024] = f;
}
__global__ void k_scan1(const float* __restrict__ iin, const float* __restrict__ fin,
                        int ld, float* __restrict__ Fo, float* __restrict__ Ho, int Nt, int L){
  int c = blockIdx.x*256 + threadIdx.x;
  int ch = blockIdx.y, b = blockIdx.z;
  float h = 0.f, F = 1.f;
  size_t base = ((size_t)b*Nt + (size_t)ch*L)*ld + c;
  for(int t=0;t<L;t++){
    float ft = fin[base + (size_t)t*ld];
    float it = iin[base + (size_t)t*ld];
    h = ft*h + it; F *= ft;
  }
  int CH = Nt/L;
  size_t o = ((size_t)b*CH + ch)*DD + c;
  Fo[o]=F; Ho[o]=h;
}
__global__ void k_scan2(const float* __restrict__ Fo, const float* __restrict__ Ho,
                        float* __restrict__ carry, int CH){
  int id = blockIdx.x*256 + threadIdx.x;   // 4096
  int b = id>>10, c = id&1023;
  float h = 0.f;
  for(int ch=0; ch<CH; ch++){
    size_t o = ((size_t)b*CH + ch)*DD + c;
    carry[o] = h;
    h = Fo[o]*h + Ho[o];
  }
}
__global__ void k_scan3(const float* __restrict__ iin, const float* __restrict__ fin,
                        int ld, const float* __restrict__ carry, float* __restrict__ oo,
                        int Nt, int L){
  int c = blockIdx.x*256 + threadIdx.x;
  int ch = blockIdx.y, b = blockIdx.z;
  int CH = Nt/L;
  float h = carry[((size_t)b*CH + ch)*DD + c];
  size_t base = ((size_t)b*Nt + (size_t)ch*L)*ld + c;
  size_t obase = ((size_t)b*Nt + (size_t)ch*L)*DD + c;
  for(int t=0;t<L;t++){
    float ft = fin[base + (size_t)t*ld];
    float it = iin[base + (size_t)t*ld];
    h = ft*h + it;
    oo[obase + (size_t)t*DD] = h;
  }
}
// o' = rms(o)*gn*g*sigmoid(g), g strided
__global__ void k_oprime(const float* __restrict__ o, const float* __restrict__ g, int gld,
                         const float* __restrict__ gn, float* __restrict__ outp){
  __shared__ float red[4];
  int r = blockIdx.x;
  float ss = 0.f;
  for(int k=threadIdx.x;k<1024;k+=256){ float v=o[(size_t)r*1024+k]; ss += v*v; }
  ss = wred_sum(ss);
  if((threadIdx.x&63)==0) red[threadIdx.x>>6]=ss;
  __syncthreads();
  float tot = red[0]+red[1]+red[2]+red[3];
  float rinv = 1.f/sqrtf(tot*(1.f/1024.f) + 1e-6f);
  for(int k=threadIdx.x;k<1024;k+=256){
    float gv = g[(size_t)r*gld+k];
    float sig = 1.f/(1.f+__expf(-gv));
    outp[(size_t)r*1024+k] = o[(size_t)r*1024+k]*rinv*gn[k]*gv*sig;
  }
}

// =====================================================================
extern "C" void kernel_launch(void* const* d_in, const int* in_sizes, int n_in,
                              void* d_out, int out_size, void* d_ws, size_t ws_size,
                              hipStream_t stream){
  const float* X     = (const float*)d_in[0];
  const float* Y     = (const float*)d_in[1];
  const float* C     = (const float*)d_in[2];
  const float* ADA_W = (const float*)d_in[3];
  const float* ADA_B = (const float*)d_in[4];
  const float* LNX_G = (const float*)d_in[5];
  const float* LNX_B = (const float*)d_in[6];
  const float* LNY_G = (const float*)d_in[7];
  const float* LNY_B = (const float*)d_in[8];
  const float* CAX_WQKV=(const float*)d_in[9];
  const float* CAX_MAG =(const float*)d_in[10];
  const float* CAX_LA  =(const float*)d_in[11];
  const float* CAX_LB  =(const float*)d_in[12];
  const float* CAX_WP  =(const float*)d_in[13];
  const float* CAY_WQKV=(const float*)d_in[14];
  const float* CAY_MAG =(const float*)d_in[15];
  const float* CAY_LA  =(const float*)d_in[16];
  const float* CAY_LB  =(const float*)d_in[17];
  const float* CAY_WP  =(const float*)d_in[18];
  const float* AX_WI = (const float*)d_in[19];
  const float* AX_WF = (const float*)d_in[20];
  const float* AX_WG = (const float*)d_in[21];
  const float* AX_WO = (const float*)d_in[22];
  const float* AX_GN = (const float*)d_in[23];
  const float* AY_WI = (const float*)d_in[24];
  const float* AY_WF = (const float*)d_in[25];
  const float* AY_WG = (const float*)d_in[26];
  const float* AY_WO = (const float*)d_in[27];
  const float* AY_GN = (const float*)d_in[28];
  const float* MX_WG = (const float*)d_in[29];
  const float* MX_WD = (const float*)d_in[30];
  const float* MY_WG = (const float*)d_in[31];
  const float* MY_WD = (const float*)d_in[32];

  float* OUTX = (float*)d_out;
  float* OUTY = OUTX + (size_t)4096*1024;

  // ---- workspace layout ----
  char* base = (char*)d_ws;
  size_t cur = 0;
  auto alloc = [&](size_t bytes)->char*{
    char* p = base + cur; cur += (bytes + 255) & ~(size_t)255; return p; };
  double* WSUM  = (double*)alloc(32*sizeof(double));
  float* WSCALE = (float*)alloc(32*sizeof(float));
  float* WRECIP = (float*)alloc(32*sizeof(float));
  float* MOD    = (float*)alloc((size_t)4*6144*4);
  float* AROW   = (float*)alloc((size_t)4096*4);
  u16*   WQ     = (u16*)alloc((size_t)40370176*2);
  u16*   AQ     = (u16*)alloc((size_t)4096*2816*2);
  float* XN     = (float*)alloc((size_t)4096*1024*4);
  float* YN     = (float*)alloc((size_t)1024*1024*4);
  float* BUFA   = (float*)alloc((size_t)4096*5632*4);
  float* BUFE   = (float*)alloc((size_t)4096*1024*4);
  float* BUFF   = (float*)alloc((size_t)4096*1024*4);
  float* T16    = (float*)alloc((size_t)4096*16*4);
  float* SCF    = (float*)alloc((size_t)4*16*1024*4);
  float* SCH    = (float*)alloc((size_t)4*16*1024*4);
  float* SCC    = (float*)alloc((size_t)4*16*1024*4);
  (void)ws_size; (void)in_sizes; (void)n_in; (void)out_size;

  // attention bf16 buffers + hgrn packed buffer alias BUFA (disjoint liveness)
  u16* Qb = (u16*)BUFA;
  u16* Kb = Qb + (size_t)4194304;
  u16* Vb = Kb + (size_t)4194304;
  float* QG = BUFA;

  // ---- weight table ----
  const float* wptr[17] = {ADA_W, CAX_WQKV, CAX_WP, CAY_WQKV, CAY_WP,
                           AX_WI, AX_WF, AX_WG, AX_WO,
                           AY_WI, AY_WF, AY_WG, AY_WO,
                           MX_WG, MX_WD, MY_WG, MY_WD};
  const size_t wn[17] = {6291456,3145728,1048576,3145728,1048576,
                         1048576,1048576,1048576,1048576,
                         1048576,1048576,1048576,1048576,
                         5767168,2883584,5767168,2883584};
  size_t woff[17]; { size_t o=0; for(int j=0;j<17;j++){ woff[j]=o; o+=wn[j]; } }

  WT wt; Counts cnt;
  for(int j=0;j<17;j++){
    wt.p[j] = wptr[j]; wt.n4[j] = (u32)(wn[j]/4); wt.off4[j] = (u32)(woff[j]/4);
    cnt.c[j] = (float)wn[j];
  }
  hipMemsetAsync(WSUM, 0, 17*sizeof(double), stream);
  k_wabs_all<<<dim3(64,17),256,0,stream>>>(wt, WSUM);
  k_wfin<<<1,32,0,stream>>>(WSUM, WSCALE, WRECIP, cnt, 17);
  k_wquant_all<<<dim3(128,17),256,0,stream>>>(wt, WRECIP, WQ);

  auto gemm = [&](int slot, const u16* aq, int M, int N, int K, int mode,
                  int wshift, int ntshift,
                  const float* bias, const float* gate,
                  const float* t16, const float* lbm, const float* mag,
                  float* out){
    int nwg = (N/128) * ((M+127)/128);
    k_gemm<<<nwg,256,0,stream>>>(aq, AROW, WQ+woff[slot], WSCALE+slot, wshift,
        M, N, K, mode, ntshift, bias, gate, t16, lbm, mag, Qb, Kb, Vb, out);
  };

  // ---- mod = bitlinear(silu(c), ada_w, ada_b) ----
  k_quant<<<4,256,0,stream>>>(C, 1024, 1024, 1, nullptr, nullptr, 1, AQ, AROW);
  gemm(0, AQ, 4, 6144, 1024, 1, 13, 10, ADA_B, nullptr, nullptr, nullptr, nullptr, MOD);

  // ---- layernorms + residual init ----
  k_ln<<<4096,256,0,stream>>>(X, LNX_G, LNX_B, XN);
  k_ln<<<1024,256,0,stream>>>(Y, LNY_G, LNY_B, YN);
  k_copy<<<4096,256,0,stream>>>(X, OUTX, (size_t)1048576);
  k_copy<<<1024,256,0,stream>>>(Y, OUTY, (size_t)262144);

  const float* G1 = MOD + 2048;   // gate_msa
  const float* G2 = MOD + 5120;   // gate_mlp

  // ---- dora attn x ----
  k_quant<<<4096,256,0,stream>>>(XN, 1024, 1024, 1024, nullptr, nullptr, 0, AQ, AROW);
  k_a1<<<256,256,0,stream>>>(XN, CAX_LA, T16, 4096);
  gemm(1, AQ, 4096, 3072, 1024, 3, 13, 10, nullptr, nullptr, T16, CAX_LB, CAX_MAG, nullptr);
  k_attn2<<<dim3(16,64),256,0,stream>>>(Qb, Kb, Vb, BUFF, 1024);
  k_quant<<<4096,256,0,stream>>>(BUFF, 1024, 1024, 1024, nullptr, nullptr, 0, AQ, AROW);
  gemm(2, AQ, 4096, 1024, 1024, 2, 13, 10, nullptr, G1, nullptr, nullptr, nullptr, OUTX);

  // ---- dora attn y ----
  k_quant<<<1024,256,0,stream>>>(YN, 1024, 1024, 256, nullptr, nullptr, 0, AQ, AROW);
  k_a1<<<64,256,0,stream>>>(YN, CAY_LA, T16, 1024);
  gemm(3, AQ, 1024, 3072, 1024, 3, 13, 8, nullptr, nullptr, T16, CAY_LB, CAY_MAG, nullptr);
  k_attn2<<<dim3(4,64),256,0,stream>>>(Qb, Kb, Vb, BUFF, 256);
  k_quant<<<1024,256,0,stream>>>(BUFF, 1024, 1024, 256, nullptr, nullptr, 0, AQ, AROW);
  gemm(4, AQ, 1024, 1024, 1024, 2, 13, 8, nullptr, G1, nullptr, nullptr, nullptr, OUTY);

  // ---- hgrn x (fused i/f/g GEMM, N=3072, per-block weight scale) ----
  k_quant<<<4096,256,0,stream>>>(XN, 1024, 1024, 1024, MOD, MOD+1024, 0, AQ, AROW);
  gemm(5, AQ, 4096, 3072, 1024, 0, 10, 10, nullptr, nullptr, nullptr, nullptr, nullptr, QG);
  k_gatei<<<16384,256,0,stream>>>(QG, 4194304);
  k_scan1<<<dim3(4,16,4),256,0,stream>>>(QG, QG+1024, 3072, SCF, SCH, 1024, 64);
  k_scan2<<<16,256,0,stream>>>(SCF, SCH, SCC, 16);
  k_scan3<<<dim3(4,16,4),256,0,stream>>>(QG, QG+1024, 3072, SCC, BUFE, 1024, 64);
  k_oprime<<<4096,256,0,stream>>>(BUFE, QG+2048, 3072, AX_GN, BUFF);
  k_quant<<<4096,256,0,stream>>>(BUFF, 1024, 1024, 1024, nullptr, nullptr, 0, AQ, AROW);
  gemm(8, AQ, 4096, 1024, 1024, 2, 13, 10, nullptr, G1, nullptr, nullptr, nullptr, OUTX);

  // ---- hgrn y ----
  k_quant<<<1024,256,0,stream>>>(YN, 1024, 1024, 256, MOD, MOD+1024, 0, AQ, AROW);
  gemm(9, AQ, 1024, 3072, 1024, 0, 10, 8, nullptr, nullptr, nullptr, nullptr, nullptr, QG);
  k_gatei<<<4096,256,0,stream>>>(QG, 1048576);
  k_scan1<<<dim3(4,16,4),256,0,stream>>>(QG, QG+1024, 3072, SCF, SCH, 256, 16);
  k_scan2<<<16,256,0,stream>>>(SCF, SCH, SCC, 16);
  k_scan3<<<dim3(4,16,4),256,0,stream>>>(QG, QG+1024, 3072, SCC, BUFE, 256, 16);
  k_oprime<<<1024,256,0,stream>>>(BUFE, QG+2048, 3072, AY_GN, BUFF);
  k_quant<<<1024,256,0,stream>>>(BUFF, 1024, 1024, 256, nullptr, nullptr, 0, AQ, AROW);
  gemm(12, AQ, 1024, 1024, 1024, 2, 13, 8, nullptr, G1, nullptr, nullptr, nullptr, OUTY);

  // ---- mlp x ----
  k_ln<<<4096,256,0,stream>>>(OUTX, LNX_G, LNX_B, XN);
  k_quant<<<4096,256,0,stream>>>(XN, 1024, 1024, 1024, MOD+3072, MOD+4096, 0, AQ, AROW);
  gemm(13, AQ, 4096, 5632, 1024, 0, 13, 10, nullptr, nullptr, nullptr, nullptr, nullptr, BUFA);
  k_quant<<<4096,256,0,stream>>>(BUFA, 5632, 2816, 1024, nullptr, nullptr, 2, AQ, AROW);
  gemm(14, AQ, 4096, 1024, 2816, 2, 13, 10, nullptr, G2, nullptr, nullptr, nullptr, OUTX);

  // ---- mlp y ----
  k_ln<<<1024,256,0,stream>>>(OUTY, LNY_G, LNY_B, YN);
  k_quant<<<1024,256,0,stream>>>(YN, 1024, 1024, 256, MOD+3072, MOD+4096, 0, AQ, AROW);
  gemm(15, AQ, 1024, 5632, 1024, 0, 13, 8, nullptr, nullptr, nullptr, nullptr, nullptr, BUFA);
  k_quant<<<1024,256,0,stream>>>(BUFA, 5632, 2816, 256, nullptr, nullptr, 2, AQ, AROW);
  gemm(16, AQ, 1024, 1024, 2816, 2, 13, 8, nullptr, G2, nullptr, nullptr, nullptr, OUTY);
}

// Round 4
// 1525.553 us; speedup vs baseline: 1.4484x; 1.0897x over previous
//
#include <hip/hip_runtime.h>

typedef unsigned short u16;
typedef unsigned int u32;
typedef __bf16 bf8 __attribute__((ext_vector_type(8)));
typedef float f32x4 __attribute__((ext_vector_type(4)));

#define DD 1024

// ---------- helpers ----------
__device__ __forceinline__ u16 f2bf(float x){
  u32 u = __float_as_uint(x);
  u += 0x7fff + ((u >> 16) & 1);
  return (u16)(u >> 16);
}
__device__ __forceinline__ float bf2f(u16 x){
  u32 u = ((u32)x) << 16;
  return __uint_as_float(u);
}
__device__ __forceinline__ float wred_sum(float v){
  #pragma unroll
  for(int m=32;m;m>>=1) v += __shfl_xor(v,m);
  return v;
}
__device__ __forceinline__ float wred_max(float v){
  #pragma unroll
  for(int m=32;m;m>>=1) v = fmaxf(v,__shfl_xor(v,m));
  return v;
}
__device__ __forceinline__ double wred_sum_d(double v){
  #pragma unroll
  for(int m=32;m;m>>=1) v += __shfl_xor(v,m);
  return v;
}
__device__ __forceinline__ void gload16(const void* g, void* l){
  __builtin_amdgcn_global_load_lds(
      (const __attribute__((address_space(1))) u32*)g,
      (__attribute__((address_space(3))) u32*)l, 16, 0, 0);
}

// ---------- batched weight scale: sum |w| (f64 accum) ----------
struct WT { const float* p[17]; u32 n4[17]; u32 off4[17]; };

__global__ void k_wabs_all(WT wt, double* __restrict__ wsum){
  int j = blockIdx.y;
  const float4* w = (const float4*)wt.p[j];
  u32 n4 = wt.n4[j];
  double s = 0.0;
  for(u32 i=blockIdx.x*256+threadIdx.x; i<n4; i+=gridDim.x*256){
    float4 v = w[i];
    s += (double)(fabsf(v.x)+fabsf(v.y)) + (double)(fabsf(v.z)+fabsf(v.w));
  }
  s = wred_sum_d(s);
  __shared__ double red[4];
  if((threadIdx.x&63)==0) red[threadIdx.x>>6]=s;
  __syncthreads();
  if(threadIdx.x==0) atomicAdd(wsum+j, red[0]+red[1]+red[2]+red[3]);
}

struct Counts{ float c[17]; };
__global__ void k_wfin(const double* __restrict__ wsum, float* __restrict__ wscale,
                       float* __restrict__ wrecip, Counts cnt, int nw){
  int j = threadIdx.x;
  if(j < nw){
    float m = (float)(wsum[j] / (double)cnt.c[j]);
    m = fmaxf(m, 1e-5f);
    wscale[j] = m;          // = 1/s  (multiplied into GEMM output)
    wrecip[j] = 1.f/m;      // = s    (used for ternarization)
  }
}

// ---------- batched weight ternarize -> bf16 {-1,0,1} ----------
__global__ void k_wquant_all(WT wt, const float* __restrict__ wrecip, u16* __restrict__ wq){
  int j = blockIdx.y;
  const float4* w = (const float4*)wt.p[j];
  uint2* outq = (uint2*)(wq + 4ull*wt.off4[j]);
  u32 n4 = wt.n4[j];
  float s = wrecip[j];
  for(u32 i=blockIdx.x*256+threadIdx.x; i<n4; i+=gridDim.x*256){
    float4 v = w[i];
    float a0 = fminf(fmaxf(rintf(v.x*s),-1.f),1.f);
    float a1 = fminf(fmaxf(rintf(v.y*s),-1.f),1.f);
    float a2 = fminf(fmaxf(rintf(v.z*s),-1.f),1.f);
    float a3 = fminf(fmaxf(rintf(v.w*s),-1.f),1.f);
    u32 p0 = (u32)f2bf(a0) | ((u32)f2bf(a1)<<16);
    u32 p1 = (u32)f2bf(a2) | ((u32)f2bf(a3)<<16);
    outq[i] = make_uint2(p0,p1);
  }
}

// ---------- activation RMS + act-quant ----------
// mode 0: plain (+optional modulate)  mode 1: silu(x)  mode 2: swiglu pair silu(x[k])*x[k+K]
__global__ void k_quant(const float* __restrict__ in, int ld, int K, int rpb,
                        const float* __restrict__ msh, const float* __restrict__ msc,
                        int mode,
                        u16* __restrict__ outq, float* __restrict__ rowsc){
  __shared__ float xr[2816];
  __shared__ float red[8];
  int r = blockIdx.x;
  const float* src = in + (size_t)r*ld;
  int b = r / rpb;
  float ss = 0.f, am = 0.f;
  for(int k=threadIdx.x; k<K; k+=256){
    float x = src[k];
    if(mode==1) x = x / (1.f + __expf(-x));
    else if(mode==2){ float yv = src[k+K]; x = (x/(1.f+__expf(-x)))*yv; }
    if(msh) x = x*(1.f + msc[(size_t)b*6144 + k]) + msh[(size_t)b*6144 + k];
    xr[k] = x;
    ss += x*x; am = fmaxf(am, fabsf(x));
  }
  ss = wred_sum(ss); am = wred_max(am);
  if((threadIdx.x&63)==0){ red[threadIdx.x>>6]=ss; red[4+(threadIdx.x>>6)]=am; }
  __syncthreads();
  ss = red[0]+red[1]+red[2]+red[3];
  am = fmaxf(fmaxf(red[4],red[5]),fmaxf(red[6],red[7]));
  float rinv = 1.f / sqrtf(ss/(float)K + 1e-6f);
  float amn = fmaxf(am*rinv, 1e-5f);
  float s = 127.f/amn;
  if(threadIdx.x==0) rowsc[r] = amn/127.f;
  for(int k=threadIdx.x; k<K; k+=256){
    float xn = xr[k]*rinv;
    float q = rintf(xn*s);
    q = fminf(fmaxf(q,-128.f),127.f);
    outq[(size_t)r*K + k] = f2bf(q);
  }
}

// ---------- layernorm ----------
__global__ void k_ln(const float* __restrict__ in, const float* __restrict__ g,
                     const float* __restrict__ bt, float* __restrict__ outp){
  __shared__ float xr[1024];
  __shared__ float red[4];
  int r = blockIdx.x;
  const float* src = in + (size_t)r*1024;
  float s1 = 0.f;
  for(int k=threadIdx.x;k<1024;k+=256){ float x=src[k]; xr[k]=x; s1+=x; }
  s1 = wred_sum(s1);
  if((threadIdx.x&63)==0) red[threadIdx.x>>6]=s1;
  __syncthreads();
  float m = (red[0]+red[1]+red[2]+red[3])*(1.f/1024.f);
  float s2 = 0.f;
  for(int k=threadIdx.x;k<1024;k+=256){ float d=xr[k]-m; s2+=d*d; }
  s2 = wred_sum(s2);
  __syncthreads();
  if((threadIdx.x&63)==0) red[threadIdx.x>>6]=s2;
  __syncthreads();
  float v = (red[0]+red[1]+red[2]+red[3])*(1.f/1024.f);
  float rstd = rsqrtf(v + 1e-5f);
  for(int k=threadIdx.x;k<1024;k+=256)
    outp[(size_t)r*1024+k] = (xr[k]-m)*rstd*g[k] + bt[k];
}

__global__ void k_copy(const float* __restrict__ in, float* __restrict__ out, size_t n4){
  size_t i = (size_t)blockIdx.x*256+threadIdx.x;
  if(i<n4) ((float4*)out)[i] = ((const float4*)in)[i];
}

// ---------- main bitlinear GEMM ----------
// mode 0: store   mode 1: store + bias[c]   mode 2: out += gate*v
// mode 3: qkv pack -> bf16 Qb/Kb/Vb head-major
// Pipeline: double-buffered LDS, stage(t+1) issued before compute(t),
// counted s_waitcnt vmcnt(8) + raw s_barrier (no compiler drain).
// LDS layout XOR-swizzled: phys slot = logical slot ^ (row&7) (16B slots),
// inverse applied on the per-lane GLOBAL source address (rule #21).
__global__ __launch_bounds__(256) void k_gemm(
    const u16* __restrict__ Aq, const float* __restrict__ arow,
    const u16* __restrict__ Wq, const float* __restrict__ wsc, int wshift,
    int M, int N, int K, int mode, int ntshift,
    const float* __restrict__ bias, const float* __restrict__ gate,
    u16* __restrict__ qb, u16* __restrict__ kb, u16* __restrict__ vb,
    float* __restrict__ out){
  __shared__ __align__(16) u16 As[2][128*64];
  __shared__ __align__(16) u16 Bs[2][128*64];
  int tid = threadIdx.x;
  int lane = tid & 63;
  int w = tid >> 6;
  // bijective XCD swizzle + column-major tile order (weight strip stays L2-hot)
  int gy = (M+127)>>7;
  int nwg = gridDim.x;
  int q8 = nwg>>3, r8 = nwg&7;
  int xcd = blockIdx.x&7, off8 = blockIdx.x>>3;
  int tile = (xcd<r8 ? xcd*(q8+1) : r8*(q8+1) + (xcd-r8)*q8) + off8;
  int tn = (tile/gy)*128;
  int tm = (tile%gy)*128;
  int wr = (w>>1)*64, wc = (w&1)*64;
  f32x4 acc[4][4];
  #pragma unroll
  for(int i=0;i<4;i++)
    #pragma unroll
    for(int j=0;j<4;j++) acc[i][j] = (f32x4){0.f,0.f,0.f,0.f};
  int lr = lane >> 3;
  int lk = ((lane & 7) ^ lr) * 8;       // swizzled k-slot on the global side
  int nk = K >> 6;

  auto stage = [&](int ktile, int buf){
    int k0 = ktile*64 + lk;
    #pragma unroll
    for(int i=0;i<4;i++){
      int r = (i*4 + w)*8 + lr;
      int gr = tm + r; gr = gr < M ? gr : M-1;   // clamp for M=4 (ada) tile
      gload16(Aq + (size_t)gr*K + k0, (char*)&As[buf][0] + (i*4+w)*1024);
      int gc = tn + r;                            // N always multiple of 128
      gload16(Wq + (size_t)gc*K + k0, (char*)&Bs[buf][0] + (i*4+w)*1024);
    }
  };
  auto compute = [&](int buf){
    #pragma unroll
    for(int kk=0;kk<2;kk++){
      int phys = ((kk*4 + (lane>>4)) ^ (lane&7)) * 8;   // row&7 == lane&7 here
      bf8 af[4], bfr[4];
      #pragma unroll
      for(int i=0;i<4;i++){
        af[i]  = *(const bf8*)&As[buf][(wr + i*16 + (lane&15))*64 + phys];
        bfr[i] = *(const bf8*)&Bs[buf][(wc + i*16 + (lane&15))*64 + phys];
      }
      #pragma unroll
      for(int i=0;i<4;i++)
        #pragma unroll
        for(int j=0;j<4;j++)
          acc[i][j] = __builtin_amdgcn_mfma_f32_16x16x32_bf16(af[i], bfr[j], acc[i][j], 0,0,0);
    }
  };

  stage(0, 0);
  int kt = 0;
  for(; kt < nk-1; ++kt){
    stage(kt+1, (kt&1)^1);
    asm volatile("s_waitcnt vmcnt(8)" ::: "memory");  // tile kt landed; kt+1 in flight
    __builtin_amdgcn_s_barrier();
    compute(kt&1);
    __builtin_amdgcn_s_barrier();
  }
  asm volatile("s_waitcnt vmcnt(0)" ::: "memory");
  __builtin_amdgcn_s_barrier();
  compute(kt&1);

  int r0 = (lane>>4)*4;
  int cc = lane & 15;
  int Nt = 1 << ntshift;
  #pragma unroll
  for(int i=0;i<4;i++){
    int rb = tm + wr + i*16 + r0;
    #pragma unroll
    for(int j=0;j<4;j++){
      int c = tn + wc + j*16 + cc;
      float wsv = wsc[c>>wshift];
      #pragma unroll
      for(int q=0;q<4;q++){
        int r = rb + q;
        if(r < M){
          float v = acc[i][j][q] * arow[r] * wsv;
          if(mode == 0) out[(size_t)r*N + c] = v;
          else if(mode == 1) out[(size_t)r*N + c] = v + bias[c];
          else if(mode == 2) out[(size_t)r*N + c] += gate[(size_t)(r>>ntshift)*6144 + c] * v;
          else {
            int which = c >> 10, c2 = c & 1023, h = c2 >> 6, d = c2 & 63;
            u16* dst = which==0 ? qb : (which==1 ? kb : vb);
            int b = r >> ntshift, n = r & (Nt-1);
            dst[((size_t)(b*16+h)*Nt + n)*64 + d] = f2bf(v);
          }
        }
      }
    }
  }
}

// ---------- low-rank path: T16 = XN @ la^T ----------
__global__ void k_a1(const float* __restrict__ xn, const float* __restrict__ la,
                     float* __restrict__ t16, int rows){
  int t = blockIdx.x*256 + threadIdx.x;
  int r = t >> 4, n = t & 15;
  if(r >= rows) return;
  const float4* a = (const float4*)(xn + (size_t)r*1024);
  const float4* b = (const float4*)(la + (size_t)n*1024);
  float s = 0.f;
  #pragma unroll 8
  for(int k=0;k<256;k++){
    float4 av=a[k], bv=b[k];
    s += av.x*bv.x + av.y*bv.y + av.z*bv.z + av.w*bv.w;
  }
  t16[(size_t)r*16 + n] = s;
}

// q += mag[h] * (T16 @ lb^T), applied to packed bf16 Q (head-major)
__global__ void k_qadd2(u16* __restrict__ qb, const float* __restrict__ t16,
                        const float* __restrict__ lb, const float* __restrict__ mag,
                        int ntshift){
  int c = blockIdx.x*256 + threadIdx.x;  // 0..1023
  int r = blockIdx.y;
  const float4* a = (const float4*)(t16 + (size_t)r*16);
  const float4* b = (const float4*)(lb + (size_t)c*16);
  float s = 0.f;
  #pragma unroll
  for(int k=0;k<4;k++){ float4 av=a[k], bv=b[k]; s += av.x*bv.x+av.y*bv.y+av.z*bv.z+av.w*bv.w; }
  int h = c>>6, d = c&63;
  int Nt = 1<<ntshift;
  int bb = r >> ntshift, n = r & (Nt-1);
  size_t qi = ((size_t)(bb*16+h)*Nt + n)*64 + d;
  qb[qi] = f2bf(bf2f(qb[qi]) + mag[h]*s);
}

// ---------- MFMA flash attention, bf16 Q/K/V head-major [bh][n][64] ----------
__global__ __launch_bounds__(256) void k_attn2(const u16* __restrict__ Qb,
    const u16* __restrict__ Kb, const u16* __restrict__ Vb,
    float* __restrict__ outp, int Nt){
  __shared__ __align__(16) u16 Ks[64*72];
  __shared__ __align__(16) u16 Vt[64*72];
  __shared__ __align__(16) u16 Ps[4*16*72];
  int tid = threadIdx.x, lane = tid&63, w = tid>>6;
  int bh = blockIdx.y;
  int q0 = blockIdx.x*64;
  size_t hb = (size_t)bh*Nt*64;
  bf8 qf[2];
  {
    const u16* qp = Qb + hb + (size_t)(q0 + w*16 + (lane&15))*64 + ((lane>>4)*8);
    qf[0] = *(const bf8*)qp;
    qf[1] = *(const bf8*)(qp+32);
  }
  float m_[4], l_[4];
  f32x4 o_[4];
  #pragma unroll
  for(int r=0;r<4;r++){ m_[r]=-1e30f; l_[r]=0.f; }
  #pragma unroll
  for(int t=0;t<4;t++) o_[t]=(f32x4){0.f,0.f,0.f,0.f};
  int ntiles = Nt >> 6;
  int sn = tid>>2, sc = tid&3;
  for(int kt=0; kt<ntiles; kt++){
    __syncthreads();
    {
      const u16* kg = Kb + hb + (size_t)(kt*64)*64;
      const u16* vg = Vb + hb + (size_t)(kt*64)*64;
      *(uint4*)&Ks[sn*72 + sc*8]      = *(const uint4*)&kg[sn*64 + sc*8];
      *(uint4*)&Ks[sn*72 + sc*8 + 32] = *(const uint4*)&kg[sn*64 + sc*8 + 32];
      uint4 v0 = *(const uint4*)&vg[sn*64 + sc*8];
      uint4 v1 = *(const uint4*)&vg[sn*64 + sc*8 + 32];
      const u16* e0 = (const u16*)&v0; const u16* e1 = (const u16*)&v1;
      #pragma unroll
      for(int j=0;j<8;j++){
        Vt[(sc*8+j)*72 + sn]    = e0[j];
        Vt[(sc*8+32+j)*72 + sn] = e1[j];
      }
    }
    __syncthreads();
    // S[16q][64k] per wave
    f32x4 s_[4];
    #pragma unroll
    for(int t=0;t<4;t++) s_[t]=(f32x4){0.f,0.f,0.f,0.f};
    #pragma unroll
    for(int c=0;c<2;c++){
      #pragma unroll
      for(int t=0;t<4;t++){
        bf8 kf = *(const bf8*)&Ks[(t*16 + (lane&15))*72 + (lane>>4)*8 + 32*c];
        s_[t] = __builtin_amdgcn_mfma_f32_16x16x32_bf16(qf[c], kf, s_[t], 0,0,0);
      }
    }
    // online softmax (state replicated over the 16 lanes of each group)
    #pragma unroll
    for(int r=0;r<4;r++){
      float mx = fmaxf(fmaxf(s_[0][r], s_[1][r]), fmaxf(s_[2][r], s_[3][r]));
      mx *= 0.125f;
      #pragma unroll
      for(int mk=1; mk<16; mk<<=1) mx = fmaxf(mx, __shfl_xor(mx, mk));
      float mn = fmaxf(m_[r], mx);
      float resc = __expf(m_[r] - mn);
      float ps = 0.f;
      #pragma unroll
      for(int t=0;t<4;t++){
        float p = __expf(s_[t][r]*0.125f - mn);
        Ps[w*1152 + ((lane>>4)*4 + r)*72 + (lane&15) + 16*t] = f2bf(p);
        ps += p;
      }
      #pragma unroll
      for(int mk=1; mk<16; mk<<=1) ps += __shfl_xor(ps, mk);
      l_[r] = l_[r]*resc + ps;
      m_[r] = mn;
      #pragma unroll
      for(int t=0;t<4;t++) o_[t][r] *= resc;
    }
    // PV: O[16q][64d] += P @ V
    #pragma unroll
    for(int c=0;c<2;c++){
      bf8 pf = *(const bf8*)&Ps[w*1152 + (lane&15)*72 + (lane>>4)*8 + 32*c];
      #pragma unroll
      for(int dt=0;dt<4;dt++){
        bf8 vf = *(const bf8*)&Vt[(dt*16 + (lane&15))*72 + (lane>>4)*8 + 32*c];
        o_[dt] = __builtin_amdgcn_mfma_f32_16x16x32_bf16(pf, vf, o_[dt], 0,0,0);
      }
    }
  }
  int b = bh >> 4, h = bh & 15;
  #pragma unroll
  for(int r=0;r<4;r++){
    float inv = 1.f/l_[r];
    int qrow = q0 + w*16 + (lane>>4)*4 + r;
    size_t ob = ((size_t)b*Nt + qrow)*1024 + (size_t)h*64;
    #pragma unroll
    for(int dt=0;dt<4;dt++)
      outp[ob + dt*16 + (lane&15)] = o_[dt][r]*inv;
  }
}

// ---------- HGRN gates + scan (i/f/g packed in rows of 3072) ----------
__global__ void k_gatei(float* __restrict__ qg, int n){
  int idx = blockIdx.x*256 + threadIdx.x;
  if(idx >= n) return;
  int r = idx >> 10, c = idx & 1023;
  size_t bi = (size_t)r*3072 + c;
  float f = 1.f/(1.f+__expf(-qg[bi+1024]));
  float x = qg[bi];
  float si = x/(1.f+__expf(-x));
  qg[bi] = si*(1.f-f);
  qg[bi+1024] = f;
}
__global__ void k_scan1(const float* __restrict__ iin, const float* __restrict__ fin,
                        int ld, float* __restrict__ Fo, float* __restrict__ Ho, int Nt, int L){
  int c = blockIdx.x*256 + threadIdx.x;
  int ch = blockIdx.y, b = blockIdx.z;
  float h = 0.f, F = 1.f;
  size_t base = ((size_t)b*Nt + (size_t)ch*L)*ld + c;
  for(int t=0;t<L;t++){
    float ft = fin[base + (size_t)t*ld];
    float it = iin[base + (size_t)t*ld];
    h = ft*h + it; F *= ft;
  }
  int CH = Nt/L;
  size_t o = ((size_t)b*CH + ch)*DD + c;
  Fo[o]=F; Ho[o]=h;
}
__global__ void k_scan2(const float* __restrict__ Fo, const float* __restrict__ Ho,
                        float* __restrict__ carry, int CH){
  int id = blockIdx.x*256 + threadIdx.x;   // 4096
  int b = id>>10, c = id&1023;
  float h = 0.f;
  for(int ch=0; ch<CH; ch++){
    size_t o = ((size_t)b*CH + ch)*DD + c;
    carry[o] = h;
    h = Fo[o]*h + Ho[o];
  }
}
__global__ void k_scan3(const float* __restrict__ iin, const float* __restrict__ fin,
                        int ld, const float* __restrict__ carry, float* __restrict__ oo,
                        int Nt, int L){
  int c = blockIdx.x*256 + threadIdx.x;
  int ch = blockIdx.y, b = blockIdx.z;
  int CH = Nt/L;
  float h = carry[((size_t)b*CH + ch)*DD + c];
  size_t base = ((size_t)b*Nt + (size_t)ch*L)*ld + c;
  size_t obase = ((size_t)b*Nt + (size_t)ch*L)*DD + c;
  for(int t=0;t<L;t++){
    float ft = fin[base + (size_t)t*ld];
    float it = iin[base + (size_t)t*ld];
    h = ft*h + it;
    oo[obase + (size_t)t*DD] = h;
  }
}
// o' = rms(o)*gn*g*sigmoid(g), g strided
__global__ void k_oprime(const float* __restrict__ o, const float* __restrict__ g, int gld,
                         const float* __restrict__ gn, float* __restrict__ outp){
  __shared__ float red[4];
  int r = blockIdx.x;
  float ss = 0.f;
  for(int k=threadIdx.x;k<1024;k+=256){ float v=o[(size_t)r*1024+k]; ss += v*v; }
  ss = wred_sum(ss);
  if((threadIdx.x&63)==0) red[threadIdx.x>>6]=ss;
  __syncthreads();
  float tot = red[0]+red[1]+red[2]+red[3];
  float rinv = 1.f/sqrtf(tot*(1.f/1024.f) + 1e-6f);
  for(int k=threadIdx.x;k<1024;k+=256){
    float gv = g[(size_t)r*gld+k];
    float sig = 1.f/(1.f+__expf(-gv));
    outp[(size_t)r*1024+k] = o[(size_t)r*1024+k]*rinv*gn[k]*gv*sig;
  }
}

// =====================================================================
extern "C" void kernel_launch(void* const* d_in, const int* in_sizes, int n_in,
                              void* d_out, int out_size, void* d_ws, size_t ws_size,
                              hipStream_t stream){
  const float* X     = (const float*)d_in[0];
  const float* Y     = (const float*)d_in[1];
  const float* C     = (const float*)d_in[2];
  const float* ADA_W = (const float*)d_in[3];
  const float* ADA_B = (const float*)d_in[4];
  const float* LNX_G = (const float*)d_in[5];
  const float* LNX_B = (const float*)d_in[6];
  const float* LNY_G = (const float*)d_in[7];
  const float* LNY_B = (const float*)d_in[8];
  const float* CAX_WQKV=(const float*)d_in[9];
  const float* CAX_MAG =(const float*)d_in[10];
  const float* CAX_LA  =(const float*)d_in[11];
  const float* CAX_LB  =(const float*)d_in[12];
  const float* CAX_WP  =(const float*)d_in[13];
  const float* CAY_WQKV=(const float*)d_in[14];
  const float* CAY_MAG =(const float*)d_in[15];
  const float* CAY_LA  =(const float*)d_in[16];
  const float* CAY_LB  =(const float*)d_in[17];
  const float* CAY_WP  =(const float*)d_in[18];
  const float* AX_WI = (const float*)d_in[19];
  const float* AX_WF = (const float*)d_in[20];
  const float* AX_WG = (const float*)d_in[21];
  const float* AX_WO = (const float*)d_in[22];
  const float* AX_GN = (const float*)d_in[23];
  const float* AY_WI = (const float*)d_in[24];
  const float* AY_WF = (const float*)d_in[25];
  const float* AY_WG = (const float*)d_in[26];
  const float* AY_WO = (const float*)d_in[27];
  const float* AY_GN = (const float*)d_in[28];
  const float* MX_WG = (const float*)d_in[29];
  const float* MX_WD = (const float*)d_in[30];
  const float* MY_WG = (const float*)d_in[31];
  const float* MY_WD = (const float*)d_in[32];

  float* OUTX = (float*)d_out;
  float* OUTY = OUTX + (size_t)4096*1024;

  // ---- workspace layout ----
  char* base = (char*)d_ws;
  size_t cur = 0;
  auto alloc = [&](size_t bytes)->char*{
    char* p = base + cur; cur += (bytes + 255) & ~(size_t)255; return p; };
  double* WSUM  = (double*)alloc(32*sizeof(double));
  float* WSCALE = (float*)alloc(32*sizeof(float));
  float* WRECIP = (float*)alloc(32*sizeof(float));
  float* MOD    = (float*)alloc((size_t)4*6144*4);
  float* AROW   = (float*)alloc((size_t)4096*4);
  u16*   WQ     = (u16*)alloc((size_t)40370176*2);
  u16*   AQ     = (u16*)alloc((size_t)4096*2816*2);
  float* XN     = (float*)alloc((size_t)4096*1024*4);
  float* YN     = (float*)alloc((size_t)1024*1024*4);
  float* BUFA   = (float*)alloc((size_t)4096*5632*4);
  float* BUFE   = (float*)alloc((size_t)4096*1024*4);
  float* BUFF   = (float*)alloc((size_t)4096*1024*4);
  float* T16    = (float*)alloc((size_t)4096*16*4);
  float* SCF    = (float*)alloc((size_t)4*16*1024*4);
  float* SCH    = (float*)alloc((size_t)4*16*1024*4);
  float* SCC    = (float*)alloc((size_t)4*16*1024*4);
  (void)ws_size; (void)in_sizes; (void)n_in; (void)out_size;

  // attention bf16 buffers + hgrn packed buffer alias BUFA (disjoint liveness)
  u16* Qb = (u16*)BUFA;
  u16* Kb = Qb + (size_t)4194304;
  u16* Vb = Kb + (size_t)4194304;
  float* QG = BUFA;

  // ---- weight table ----
  const float* wptr[17] = {ADA_W, CAX_WQKV, CAX_WP, CAY_WQKV, CAY_WP,
                           AX_WI, AX_WF, AX_WG, AX_WO,
                           AY_WI, AY_WF, AY_WG, AY_WO,
                           MX_WG, MX_WD, MY_WG, MY_WD};
  const size_t wn[17] = {6291456,3145728,1048576,3145728,1048576,
                         1048576,1048576,1048576,1048576,
                         1048576,1048576,1048576,1048576,
                         5767168,2883584,5767168,2883584};
  size_t woff[17]; { size_t o=0; for(int j=0;j<17;j++){ woff[j]=o; o+=wn[j]; } }

  WT wt; Counts cnt;
  for(int j=0;j<17;j++){
    wt.p[j] = wptr[j]; wt.n4[j] = (u32)(wn[j]/4); wt.off4[j] = (u32)(woff[j]/4);
    cnt.c[j] = (float)wn[j];
  }
  hipMemsetAsync(WSUM, 0, 17*sizeof(double), stream);
  k_wabs_all<<<dim3(64,17),256,0,stream>>>(wt, WSUM);
  k_wfin<<<1,32,0,stream>>>(WSUM, WSCALE, WRECIP, cnt, 17);
  k_wquant_all<<<dim3(128,17),256,0,stream>>>(wt, WRECIP, WQ);

  auto gemm = [&](int slot, const u16* aq, int M, int N, int K, int mode,
                  int wshift, int ntshift,
                  const float* bias, const float* gate, float* out){
    int nwg = (N/128) * ((M+127)/128);
    k_gemm<<<nwg,256,0,stream>>>(aq, AROW, WQ+woff[slot], WSCALE+slot, wshift,
        M, N, K, mode, ntshift, bias, gate, Qb, Kb, Vb, out);
  };

  // ---- mod = bitlinear(silu(c), ada_w, ada_b) ----
  k_quant<<<4,256,0,stream>>>(C, 1024, 1024, 1, nullptr, nullptr, 1, AQ, AROW);
  gemm(0, AQ, 4, 6144, 1024, 1, 13, 10, ADA_B, nullptr, MOD);

  // ---- layernorms + residual init ----
  k_ln<<<4096,256,0,stream>>>(X, LNX_G, LNX_B, XN);
  k_ln<<<1024,256,0,stream>>>(Y, LNY_G, LNY_B, YN);
  k_copy<<<4096,256,0,stream>>>(X, OUTX, (size_t)1048576);
  k_copy<<<1024,256,0,stream>>>(Y, OUTY, (size_t)262144);

  const float* G1 = MOD + 2048;   // gate_msa
  const float* G2 = MOD + 5120;   // gate_mlp

  // ---- dora attn x ----
  k_quant<<<4096,256,0,stream>>>(XN, 1024, 1024, 1024, nullptr, nullptr, 0, AQ, AROW);
  k_a1<<<256,256,0,stream>>>(XN, CAX_LA, T16, 4096);
  gemm(1, AQ, 4096, 3072, 1024, 3, 13, 10, nullptr, nullptr, nullptr);
  k_qadd2<<<dim3(4,4096),256,0,stream>>>(Qb, T16, CAX_LB, CAX_MAG, 10);
  k_attn2<<<dim3(16,64),256,0,stream>>>(Qb, Kb, Vb, BUFF, 1024);
  k_quant<<<4096,256,0,stream>>>(BUFF, 1024, 1024, 1024, nullptr, nullptr, 0, AQ, AROW);
  gemm(2, AQ, 4096, 1024, 1024, 2, 13, 10, nullptr, G1, OUTX);

  // ---- dora attn y ----
  k_quant<<<1024,256,0,stream>>>(YN, 1024, 1024, 256, nullptr, nullptr, 0, AQ, AROW);
  k_a1<<<64,256,0,stream>>>(YN, CAY_LA, T16, 1024);
  gemm(3, AQ, 1024, 3072, 1024, 3, 13, 8, nullptr, nullptr, nullptr);
  k_qadd2<<<dim3(4,1024),256,0,stream>>>(Qb, T16, CAY_LB, CAY_MAG, 8);
  k_attn2<<<dim3(4,64),256,0,stream>>>(Qb, Kb, Vb, BUFF, 256);
  k_quant<<<1024,256,0,stream>>>(BUFF, 1024, 1024, 256, nullptr, nullptr, 0, AQ, AROW);
  gemm(4, AQ, 1024, 1024, 1024, 2, 13, 8, nullptr, G1, OUTY);

  // ---- hgrn x (fused i/f/g GEMM, N=3072, per-block weight scale) ----
  k_quant<<<4096,256,0,stream>>>(XN, 1024, 1024, 1024, MOD, MOD+1024, 0, AQ, AROW);
  gemm(5, AQ, 4096, 3072, 1024, 0, 10, 10, nullptr, nullptr, QG);
  k_gatei<<<16384,256,0,stream>>>(QG, 4194304);
  k_scan1<<<dim3(4,16,4),256,0,stream>>>(QG, QG+1024, 3072, SCF, SCH, 1024, 64);
  k_scan2<<<16,256,0,stream>>>(SCF, SCH, SCC, 16);
  k_scan3<<<dim3(4,16,4),256,0,stream>>>(QG, QG+1024, 3072, SCC, BUFE, 1024, 64);
  k_oprime<<<4096,256,0,stream>>>(BUFE, QG+2048, 3072, AX_GN, BUFF);
  k_quant<<<4096,256,0,stream>>>(BUFF, 1024, 1024, 1024, nullptr, nullptr, 0, AQ, AROW);
  gemm(8, AQ, 4096, 1024, 1024, 2, 13, 10, nullptr, G1, OUTX);

  // ---- hgrn y ----
  k_quant<<<1024,256,0,stream>>>(YN, 1024, 1024, 256, MOD, MOD+1024, 0, AQ, AROW);
  gemm(9, AQ, 1024, 3072, 1024, 0, 10, 8, nullptr, nullptr, QG);
  k_gatei<<<4096,256,0,stream>>>(QG, 1048576);
  k_scan1<<<dim3(4,16,4),256,0,stream>>>(QG, QG+1024, 3072, SCF, SCH, 256, 16);
  k_scan2<<<16,256,0,stream>>>(SCF, SCH, SCC, 16);
  k_scan3<<<dim3(4,16,4),256,0,stream>>>(QG, QG+1024, 3072, SCC, BUFE, 256, 16);
  k_oprime<<<1024,256,0,stream>>>(BUFE, QG+2048, 3072, AY_GN, BUFF);
  k_quant<<<1024,256,0,stream>>>(BUFF, 1024, 1024, 256, nullptr, nullptr, 0, AQ, AROW);
  gemm(12, AQ, 1024, 1024, 1024, 2, 13, 8, nullptr, G1, OUTY);

  // ---- mlp x ----
  k_ln<<<4096,256,0,stream>>>(OUTX, LNX_G, LNX_B, XN);
  k_quant<<<4096,256,0,stream>>>(XN, 1024, 1024, 1024, MOD+3072, MOD+4096, 0, AQ, AROW);
  gemm(13, AQ, 4096, 5632, 1024, 0, 13, 10, nullptr, nullptr, BUFA);
  k_quant<<<4096,256,0,stream>>>(BUFA, 5632, 2816, 1024, nullptr, nullptr, 2, AQ, AROW);
  gemm(14, AQ, 4096, 1024, 2816, 2, 13, 10, nullptr, G2, OUTX);

  // ---- mlp y ----
  k_ln<<<1024,256,0,stream>>>(OUTY, LNY_G, LNY_B, YN);
  k_quant<<<1024,256,0,stream>>>(YN, 1024, 1024, 256, MOD+3072, MOD+4096, 0, AQ, AROW);
  gemm(15, AQ, 1024, 5632, 1024, 0, 13, 8, nullptr, nullptr, BUFA);
  k_quant<<<1024,256,0,stream>>>(BUFA, 5632, 2816, 256, nullptr, nullptr, 2, AQ, AROW);
  gemm(16, AQ, 1024, 1024, 2816, 2, 13, 8, nullptr, G2, OUTY);
}